// Round 2
// baseline (2656.966 us; speedup 1.0000x reference)
//
#include <hip/hip_runtime.h>

static constexpr int N_NODES = 50000;
static constexpr int N_EDGES = 640000;
static constexpr int D = 128;          // DE == DN == 128
static constexpr int NPB = 8;          // nodes per block in MLP kernel

// ---------------------------------------------------------------------------
// Phase 1: scatter-add edge features into per-node sums (src and dst) + counts
// One thread per (edge, 4-float chunk): 32 threads cover one 128-float row.
// NOTE: harness delivers integer inputs as int32 (not the reference's int64).
// ---------------------------------------------------------------------------
__global__ __launch_bounds__(256) void scatter_kernel(
    const float4* __restrict__ feat4,        // [E * 32] float4
    const int* __restrict__ eidx,            // [2, E] int32
    float* __restrict__ sum_src,             // [N, 128]
    float* __restrict__ sum_dst,             // [N, 128]
    float* __restrict__ cnt_src,             // [N]
    float* __restrict__ cnt_dst)             // [N]
{
    int t = blockIdx.x * 256 + threadIdx.x;  // 0 .. E*32-1 (grid sized exactly)
    int e = t >> 5;
    int c = t & 31;

    int s = eidx[e];
    int d = eidx[N_EDGES + e];
    float4 v = feat4[t];

    float* ps = sum_src + (size_t)s * D + c * 4;
    float* pd = sum_dst + (size_t)d * D + c * 4;
    atomicAdd(ps + 0, v.x); atomicAdd(ps + 1, v.y);
    atomicAdd(ps + 2, v.z); atomicAdd(ps + 3, v.w);
    atomicAdd(pd + 0, v.x); atomicAdd(pd + 1, v.y);
    atomicAdd(pd + 2, v.z); atomicAdd(pd + 3, v.w);

    if (c == 0) {
        atomicAdd(cnt_src + s, 1.0f);
        atomicAdd(cnt_dst + d, 1.0f);
    }
}

// ---------------------------------------------------------------------------
// Phase 2: per-node MLP.  attention = sigmoid(relu([ms, md] @ W1 + b1) @ W2 + b2)
// where ms = sum_src/max(cnt,1), md = sum_dst/max(cnt,1).
// Division by count is folded into two post-accumulation scales.
// sum_src aliases d_out: block b reads only rows [8b,8b+8) of sum_src and
// writes only the same rows of out, strictly after the reads -> no hazard.
// ---------------------------------------------------------------------------
__global__ __launch_bounds__(128) void mlp_kernel(
    const float* __restrict__ sum_src,
    const float* __restrict__ sum_dst,
    const float* __restrict__ cnt_src,
    const float* __restrict__ cnt_dst,
    const float* __restrict__ W1,   // [256, 128] row-major
    const float* __restrict__ b1,   // [128]
    const float* __restrict__ W2,   // [128, 128] row-major
    const float* __restrict__ b2,   // [128]
    float* __restrict__ out)        // [N, 128]
{
    __shared__ float hs[NPB][D];

    const int j = threadIdx.x;              // output column 0..127
    const int base = blockIdx.x * NPB;      // N divisible by NPB (50000 = 6250*8)

    float acc1[NPB], acc2[NPB];
#pragma unroll
    for (int n = 0; n < NPB; ++n) { acc1[n] = 0.0f; acc2[n] = 0.0f; }

    const float bb1 = b1[j];

#pragma unroll 4
    for (int k = 0; k < D; ++k) {
        float w1a = W1[k * D + j];           // rows 0..127   (subject half)
        float w1b = W1[(D + k) * D + j];     // rows 128..255 (object half)
#pragma unroll
        for (int n = 0; n < NPB; ++n) {
            acc1[n] = fmaf(sum_src[(size_t)(base + n) * D + k], w1a, acc1[n]);
            acc2[n] = fmaf(sum_dst[(size_t)(base + n) * D + k], w1b, acc2[n]);
        }
    }

#pragma unroll
    for (int n = 0; n < NPB; ++n) {
        float rs = 1.0f / fmaxf(cnt_src[base + n], 1.0f);
        float rd = 1.0f / fmaxf(cnt_dst[base + n], 1.0f);
        hs[n][j] = fmaxf(bb1 + acc1[n] * rs + acc2[n] * rd, 0.0f);
    }
    __syncthreads();

    float o[NPB];
    const float bb2 = b2[j];
#pragma unroll
    for (int n = 0; n < NPB; ++n) o[n] = bb2;

#pragma unroll 4
    for (int k = 0; k < D; ++k) {
        float w = W2[k * D + j];
#pragma unroll
        for (int n = 0; n < NPB; ++n) o[n] = fmaf(hs[n][k], w, o[n]);
    }

#pragma unroll
    for (int n = 0; n < NPB; ++n) {
        float x = o[n];
        out[(size_t)(base + n) * D + j] = 1.0f / (1.0f + __expf(-x));
    }
}

// ---------------------------------------------------------------------------
extern "C" void kernel_launch(void* const* d_in, const int* in_sizes, int n_in,
                              void* d_out, int out_size, void* d_ws, size_t ws_size,
                              hipStream_t stream) {
    // setup_inputs dict order:
    //   0: edge_features [E,128] f32
    //   1: W1 [256,128] f32
    //   2: b1 [128] f32
    //   3: W2 [128,128] f32
    //   4: b2 [128] f32
    //   5: edge_index [2,E] int32 (harness converts integers to int32)
    //   6: num_nodes (scalar)
    const float* feat = (const float*)d_in[0];
    const float* W1   = (const float*)d_in[1];
    const float* b1   = (const float*)d_in[2];
    const float* W2   = (const float*)d_in[3];
    const float* b2   = (const float*)d_in[4];
    const int*   eidx = (const int*)d_in[5];
    float* out = (float*)d_out;

    // sum_src lives in d_out (25.6 MB); d_ws holds sum_dst + counts (~26 MB).
    float* sum_src = out;
    float* sum_dst = (float*)d_ws;
    float* cnt_src = sum_dst + (size_t)N_NODES * D;
    float* cnt_dst = cnt_src + N_NODES;

    size_t ws_zero_bytes = ((size_t)N_NODES * D + (size_t)N_NODES * 2) * sizeof(float);
    hipMemsetAsync(d_out, 0, (size_t)N_NODES * D * sizeof(float), stream);
    hipMemsetAsync(d_ws, 0, ws_zero_bytes, stream);

    // 640000 edges * 32 chunks / 256 threads = 80000 blocks (exact)
    scatter_kernel<<<(N_EDGES * 32) / 256, 256, 0, stream>>>(
        (const float4*)feat, eidx, sum_src, sum_dst, cnt_src, cnt_dst);

    // 50000 / 8 = 6250 blocks (exact)
    mlp_kernel<<<N_NODES / NPB, 128, 0, stream>>>(
        sum_src, sum_dst, cnt_src, cnt_dst, W1, b1, W2, b2, out);
}

// Round 3
// 853.552 us; speedup vs baseline: 3.1128x; 3.1128x over previous
//
#include <hip/hip_runtime.h>

static constexpr int N = 50000;    // nodes
static constexpr int E = 640000;   // edges
static constexpr int D = 128;      // feature dim (DE == DN)
static constexpr int NPB = 8;      // nodes per block in fused kernel

// ---------------------------------------------------------------------------
// Phase 1: degree histogram (int atomics, 400 KB targets -> L2-resident)
// ---------------------------------------------------------------------------
__global__ __launch_bounds__(256) void hist_kernel(
    const int* __restrict__ eidx, int* __restrict__ hist_s, int* __restrict__ hist_d)
{
    int e = blockIdx.x * 256 + threadIdx.x;   // grid sized exactly E/256
    atomicAdd(&hist_s[eidx[e]], 1);
    atomicAdd(&hist_d[eidx[E + e]], 1);
}

// ---------------------------------------------------------------------------
// Phase 2: exclusive scan of the two histograms. Grid = 2 blocks (one per
// direction), 1024 threads each; thread-0 serial scan of 1024 partials.
// Writes both the start offsets (offs) and a working copy (run) for phase 3.
// ---------------------------------------------------------------------------
__global__ __launch_bounds__(1024) void scan_kernel(
    const int* __restrict__ hist_s, int* __restrict__ offs_s, int* __restrict__ run_s,
    const int* __restrict__ hist_d, int* __restrict__ offs_d, int* __restrict__ run_d)
{
    const int* hist = blockIdx.x ? hist_d : hist_s;
    int* offs = blockIdx.x ? offs_d : offs_s;
    int* run  = blockIdx.x ? run_d  : run_s;

    __shared__ int part[1024];
    const int t = threadIdx.x;
    const int chunk = (N + 1023) / 1024;          // 49
    const int lo = t * chunk;
    const int hi = min(lo + chunk, N);

    int s = 0;
    for (int i = lo; i < hi; ++i) s += hist[i];
    part[t] = s;
    __syncthreads();
    if (t == 0) {
        int acc = 0;
        for (int i = 0; i < 1024; ++i) { int v = part[i]; part[i] = acc; acc += v; }
    }
    __syncthreads();
    int acc = part[t];
    for (int i = lo; i < hi; ++i) { offs[i] = acc; run[i] = acc; acc += hist[i]; }
}

// ---------------------------------------------------------------------------
// Phase 3: scatter edge ids into per-node CSR lists (int atomics for slots)
// ---------------------------------------------------------------------------
__global__ __launch_bounds__(256) void ids_kernel(
    const int* __restrict__ eidx, int* __restrict__ run_s, int* __restrict__ run_d,
    int* __restrict__ ids_s, int* __restrict__ ids_d)
{
    int e = blockIdx.x * 256 + threadIdx.x;
    int s = eidx[e];
    int d = eidx[E + e];
    ids_s[atomicAdd(&run_s[s], 1)] = e;
    ids_d[atomicAdd(&run_d[d], 1)] = e;
}

// ---------------------------------------------------------------------------
// Phase 4: fused gather(mean) + 2-layer MLP + sigmoid.
// Block = 128 threads, NPB=8 nodes. Thread j owns feature/output column j.
// Means live in LDS (float4-aligned) and are broadcast-read via ds_read_b128
// in the GEMM loops; weight rows are coalesced and L2-hot.
// ---------------------------------------------------------------------------
__global__ __launch_bounds__(128) void fused_kernel(
    const float* __restrict__ feat,            // [E, 128]
    const int* __restrict__ ids_s, const int* __restrict__ offs_s, const int* __restrict__ hist_s,
    const int* __restrict__ ids_d, const int* __restrict__ offs_d, const int* __restrict__ hist_d,
    const float* __restrict__ W1,              // [256, 128] row-major
    const float* __restrict__ b1,              // [128]
    const float* __restrict__ W2,              // [128, 128] row-major
    const float* __restrict__ b2,              // [128]
    float* __restrict__ out)                   // [N, 128]
{
    __shared__ float4 m4[NPB][2 * D / 4];      // [n][0..63]=src mean, [64..127]=dst mean
    __shared__ float4 h4[NPB][D / 4];

    const int j = threadIdx.x;                 // column 0..127
    const int base = blockIdx.x * NPB;         // 50000 = 6250 * 8, exact

    // ---- gather means ----
    for (int n = 0; n < NPB; ++n) {
        const int node = base + n;
        float* mrow = (float*)&m4[n][0];

        int st = offs_s[node], dg = hist_s[node];
        float a = 0.0f;
        #pragma unroll 4
        for (int i = 0; i < dg; ++i)
            a += feat[(size_t)ids_s[st + i] * D + j];
        mrow[j] = a * (1.0f / (float)(dg > 0 ? dg : 1));

        st = offs_d[node]; dg = hist_d[node];
        a = 0.0f;
        #pragma unroll 4
        for (int i = 0; i < dg; ++i)
            a += feat[(size_t)ids_d[st + i] * D + j];
        mrow[D + j] = a * (1.0f / (float)(dg > 0 ? dg : 1));
    }
    __syncthreads();

    // ---- layer 1: h = relu([ms, md] @ W1 + b1) ----
    float acc[NPB];
    const float bb1 = b1[j];
    #pragma unroll
    for (int n = 0; n < NPB; ++n) acc[n] = bb1;

    for (int k4 = 0; k4 < 2 * D / 4; ++k4) {
        const int k = k4 * 4;
        float w0 = W1[(k + 0) * D + j];
        float w1v = W1[(k + 1) * D + j];
        float w2v = W1[(k + 2) * D + j];
        float w3v = W1[(k + 3) * D + j];
        #pragma unroll
        for (int n = 0; n < NPB; ++n) {
            float4 mv = m4[n][k4];
            acc[n] = fmaf(mv.x, w0, acc[n]);
            acc[n] = fmaf(mv.y, w1v, acc[n]);
            acc[n] = fmaf(mv.z, w2v, acc[n]);
            acc[n] = fmaf(mv.w, w3v, acc[n]);
        }
    }
    #pragma unroll
    for (int n = 0; n < NPB; ++n)
        ((float*)&h4[n][0])[j] = fmaxf(acc[n], 0.0f);
    __syncthreads();

    // ---- layer 2: out = sigmoid(h @ W2 + b2) ----
    float o[NPB];
    const float bb2 = b2[j];
    #pragma unroll
    for (int n = 0; n < NPB; ++n) o[n] = bb2;

    for (int k4 = 0; k4 < D / 4; ++k4) {
        const int k = k4 * 4;
        float w0 = W2[(k + 0) * D + j];
        float w1v = W2[(k + 1) * D + j];
        float w2v = W2[(k + 2) * D + j];
        float w3v = W2[(k + 3) * D + j];
        #pragma unroll
        for (int n = 0; n < NPB; ++n) {
            float4 hv = h4[n][k4];
            o[n] = fmaf(hv.x, w0, o[n]);
            o[n] = fmaf(hv.y, w1v, o[n]);
            o[n] = fmaf(hv.z, w2v, o[n]);
            o[n] = fmaf(hv.w, w3v, o[n]);
        }
    }
    #pragma unroll
    for (int n = 0; n < NPB; ++n)
        out[(size_t)(base + n) * D + j] = 1.0f / (1.0f + __expf(-o[n]));
}

// ---------------------------------------------------------------------------
extern "C" void kernel_launch(void* const* d_in, const int* in_sizes, int n_in,
                              void* d_out, int out_size, void* d_ws, size_t ws_size,
                              hipStream_t stream) {
    // inputs: 0 edge_features f32 [E,128], 1 W1 [256,128], 2 b1 [128],
    //         3 W2 [128,128], 4 b2 [128], 5 edge_index int32 [2,E], 6 num_nodes
    const float* feat = (const float*)d_in[0];
    const float* W1   = (const float*)d_in[1];
    const float* b1   = (const float*)d_in[2];
    const float* W2   = (const float*)d_in[3];
    const float* b2   = (const float*)d_in[4];
    const int*   eidx = (const int*)d_in[5];
    float* out = (float*)d_out;

    // workspace (ints): hist_s hist_d | offs_s offs_d | run_s run_d | ids_s ids_d
    int* hist_s = (int*)d_ws;
    int* hist_d = hist_s + N;
    int* offs_s = hist_d + N;
    int* offs_d = offs_s + N;
    int* run_s  = offs_d + N;
    int* run_d  = run_s + N;
    int* ids_s  = run_d + N;
    int* ids_d  = ids_s + E;
    // total: 6*N + 2*E ints = 6.3 MB

    hipMemsetAsync(hist_s, 0, 2 * N * sizeof(int), stream);

    hist_kernel<<<E / 256, 256, 0, stream>>>(eidx, hist_s, hist_d);
    scan_kernel<<<2, 1024, 0, stream>>>(hist_s, offs_s, run_s, hist_d, offs_d, run_d);
    ids_kernel<<<E / 256, 256, 0, stream>>>(eidx, run_s, run_d, ids_s, ids_d);
    fused_kernel<<<N / NPB, 128, 0, stream>>>(
        feat, ids_s, offs_s, hist_s, ids_d, offs_d, hist_d,
        W1, b1, W2, b2, out);
}